// Round 10
// baseline (808.035 us; speedup 1.0000x reference)
//
#include <hip/hip_runtime.h>
#include <math.h>

#define NB 16
#define NSY 180
#define NSX 360
#define NCIN 16
#define NW 32
#define NMODES 32
#define NPIX (NSY*NSX)     // 64800
#define NPTS (NB*NPIX)     // 1036800

typedef unsigned int uint;
typedef unsigned short ushort;
typedef __attribute__((ext_vector_type(8))) short bf16x8;
typedef __attribute__((ext_vector_type(4))) float f32x4;

union U4 { uint u[4]; bf16x8 v; };

// tanh-gelu, exp2-folded: v*sigmoid(1.5957691*(v+0.044715 v^3))
__device__ __forceinline__ float gelu_f(float v){
  float u = v*(-2.3021681f - 0.10295335f*v*v);
  return v * __builtin_amdgcn_rcpf(1.f + exp2f(u));
}
__device__ __forceinline__ ushort f2bf(float x){
  uint u = __float_as_uint(x);
  return (ushort)((u + 0x7FFFu + ((u>>16)&1u)) >> 16);
}
// single-instruction packed f32->bf16 RNE (gfx950 v_cvt_pk_bf16_f32; a->low16)
__device__ __forceinline__ uint packbf2(float a, float b){
  uint r;
  asm("v_cvt_pk_bf16_f32 %0, %1, %2" : "=v"(r) : "v"(a), "v"(b));
  return r;
}
__device__ __forceinline__ float bf2f(ushort u){
  return __uint_as_float(((uint)u) << 16);
}
__device__ __forceinline__ uint addbf2(uint h, uint a){
  return packbf2(bf2f((ushort)(h & 0xffffu)) + bf2f((ushort)(a & 0xffffu)),
                 bf2f((ushort)(h >> 16))     + bf2f((ushort)(a >> 16)));
}

// ---------------- prep: bf16 Vandermonde (zero-padded), grid, fc1^T, w2 bf16 ----------------
__global__ __launch_bounds__(256) void k_prep(const float* __restrict__ sx,
    const float* __restrict__ sy, const float* __restrict__ fc1_w,
    const float* __restrict__ w2m,
    ushort* __restrict__ Abfy, ushort* __restrict__ Abfx,
    ushort* __restrict__ VyCT, ushort* __restrict__ VxCT,
    ushort* __restrict__ f1Tbf, ushort* __restrict__ w2bf,
    float* __restrict__ gx, float* __restrict__ gy){
  int idx = blockIdx.x*256 + threadIdx.x;
  float sx0 = sx[0], sxL = sx[NSX-1];
  float sy0 = sy[0], syL = sy[NSY-1];
  const float scy = 0.07453559924999298980f;   // 1/sqrt(180)
  const float scx = 0.05270462766947298886f;   // 1/sqrt(360)
  if (idx < NSX) gx[idx] = (sx[idx]-sx0)/sxL;
  if (idx < NSY) gy[idx] = (sy[idx]-sy0)/syL;
  if (idx < 64*192){
    int kri = idx/192, m = idx%192;
    float val = 0.f;
    if (m < NSY){
      int k = kri>>1;
      float p = (sy[m]-sy0)/(syL-sy0);
      float ang = -6.2831853071795864769f*(float)k*p;
      val = ((kri&1)? sinf(ang) : cosf(ang))*scy;
    }
    Abfy[idx] = f2bf(val);
  }
  if (idx < 192*64){
    int m = idx/64, kri = idx%64;
    float val = 0.f;
    if (m < NSY){
      int k = kri>>1;
      float p = (sy[m]-sy0)/(syL-sy0);
      float ang = -6.2831853071795864769f*(float)k*p;
      val = ((kri&1)? sinf(ang) : cosf(ang))*scy;
    }
    VyCT[idx] = f2bf(val);
  }
  if (idx < 64*384){
    int kri = idx/384, n = idx%384;
    float val = 0.f;
    if (n < NSX){
      int k = kri>>1;
      float p = (sx[n]-sx0)/(sxL-sx0);
      float ang = -6.2831853071795864769f*(float)k*p;
      val = ((kri&1)? sinf(ang) : cosf(ang))*scx;
    }
    Abfx[idx] = f2bf(val);
  }
  if (idx < 384*64){
    int n = idx/64, kri = idx%64;
    float val = 0.f;
    if (n < NSX){
      int k = kri>>1;
      float p = (sx[n]-sx0)/(sxL-sx0);
      float ang = -6.2831853071795864769f*(float)k*p;
      val = ((kri&1)? sinf(ang) : cosf(ang))*scx;
    }
    VxCT[idx] = f2bf(val);
  }
  if (idx < 128*32){
    int j = idx >> 5, c = idx & 31;
    f1Tbf[idx] = f2bf(fc1_w[c*128 + j]);
  }
  if (idx < 4096){
    // w2m: [4][o=32][c=32] fp32 -> bf16, same layout (B-frag reads [o][c])
    w2bf[idx] = f2bf(w2m[idx]);
  }
}

// ---------------- fold pointwise w1 into mode-mix weights -> bf16 MFMA A-matrices ----------------
// Output wAbf layout: [i(4)][half(2)][k(32)][pass(2: OR,OI)][prec(2: hi,lo)][o(32)][kk(64)]
// ushorts. Split precision: w ~= bf16(w) + bf16(w - bf16(w)) keeps ~16 mantissa
// bits, so MFMA mix matches fp32-weight accuracy. OR pass: [2in]=wR, [2in+1]=-wI.
// OI pass: [2in]=wI, [2in+1]=wR.  (B[2in]=fR, B[2in+1]=fI.)
__global__ __launch_bounds__(256) void k_fold(const float* __restrict__ fw1,
    const float* __restrict__ fw2, const float* __restrict__ w1m,
    ushort* __restrict__ wAbf){
  int id = blockIdx.x*256 + threadIdx.x;      // 0..262143
  int half = id >> 17;
  int r = id & 131071;
  int i  = r >> 15;
  int in = (r >> 10) & 31;
  int k  = (r >> 5) & 31;
  int o  = r & 31;
  const float* src = half ? fw2 : fw1;
  const float* wm  = w1m + i*1024 + o*32;
  const float* sp  = src + ((size_t)((i*32+in)*1024 + k))*2;
  float sR = 0.f, sI = 0.f;
  #pragma unroll
  for (int c=0;c<32;c++){
    float w = wm[c];
    sR += w * sp[c*64];
    sI += w * sp[c*64+1];
  }
  ushort rH = f2bf(sR);  ushort rL = f2bf(sR - bf2f(rH));
  ushort iH = f2bf(sI);  ushort iL = f2bf(sI - bf2f(iH));
  ushort nH = f2bf(-sI); ushort nL = f2bf(-sI - bf2f(nH));
  ushort* base = wAbf + (((size_t)((i*2 + half)*32 + k)) << 13);  // *8192
  int oi = o*64 + 2*in;
  base[oi]          = rH;  base[oi+1]        = nH;   // OR hi
  base[2048 + oi]   = rL;  base[2048 + oi+1] = nL;   // OR lo
  base[4096 + oi]   = iH;  base[4096 + oi+1] = rH;   // OI hi
  base[6144 + oi]   = iL;  base[6144 + oi+1] = rL;   // OI lo
}

// ---------------- fc0 -> hbf (bf16 residual stream); float4-vectorized loads ----------------
__global__ __launch_bounds__(256) void k_fc0(const float* __restrict__ x,
    const float* __restrict__ gx, const float* __restrict__ gy,
    const float* __restrict__ fw, const float* __restrict__ fb,
    ushort* __restrict__ hbf){
  int p = blockIdx.x*256 + threadIdx.x;
  if (p >= NPTS) return;
  int b = p/NPIX, r = p%NPIX, m = r/NSX, n = r%NSX;
  const float* xp = x + (size_t)p*NCIN;
  float4 x0 = *(const float4*)(xp);
  float4 x1 = *(const float4*)(xp+4);
  float4 x2 = *(const float4*)(xp+8);
  float4 x3 = *(const float4*)(xp+12);
  float xv[NCIN+2] = {x0.x,x0.y,x0.z,x0.w, x1.x,x1.y,x1.z,x1.w,
                      x2.x,x2.y,x2.z,x2.w, x3.x,x3.y,x3.z,x3.w, 0.f,0.f};
  xv[16] = gx[n]; xv[17] = gy[m];
  float acc[NW];
  #pragma unroll
  for (int o=0;o<NW;o++) acc[o] = fb[o];
  #pragma unroll
  for (int j=0;j<NCIN+2;j++){
    float v = xv[j];
    #pragma unroll
    for (int o=0;o<NW;o++) acc[o] += v*fw[j*32+o];
  }
  ushort* hq = hbf + (size_t)b*NW*NPIX + r;
  #pragma unroll
  for (int o=0;o<NW;o++) hq[(size_t)o*NPIX] = f2bf(acc[o]);
}

// ---------------- merged MFMA forward DFTs (y + x in one dispatch) ----------------
__global__ __launch_bounds__(256) void k_fwd(const ushort* __restrict__ hbf,
    const ushort* __restrict__ Abfy, const ushort* __restrict__ Abfx,
    uint* __restrict__ fty, uint* __restrict__ ftx, int b0, int ylim){
  __shared__ ushort rawS[2][32*64];   // 2 x 4KB raw tile (y-branch)
  __shared__ uint   BtS[2][64*18];    // 2 x 4.6KB packed B
  int bx = blockIdx.x;
  int tid = threadIdx.x;
  int l = tid & 63, g = tid >> 6;
  int c15 = l & 15, q = l >> 4;
  if (bx < ylim){
    int nt6 = bx % 6; int c = (bx/6) & 31; int bb = bx/192;
    int n0 = nt6*64;
    const ushort* hb = hbf + (size_t)((b0+bb)*NW + c)*NPIX;
    // cooperative tile load mapping: row r = tid>>3 (0..31), col chunk (tid&7)*8
    int yr = tid >> 3, yc = (tid & 7) << 3;
    auto ldY = [&](int ks)->uint4{
      int m = ks*32 + yr;
      int gc = n0 + yc;
      uint4 p = {0u,0u,0u,0u};
      if (m < NSY && gc < NSX) p = *(const uint4*)(hb + (size_t)m*NSX + gc);
      return p;
    };
    bf16x8 afr[6];
    #pragma unroll
    for (int ks=0; ks<6; ks++)
      afr[ks] = *(const bf16x8*)(Abfy + (size_t)(16*g + c15)*192 + ks*32 + q*8);
    f32x4 acc[4];
    #pragma unroll
    for (int t=0;t<4;t++) acc[t] = (f32x4){0.f,0.f,0.f,0.f};
    uint4 pre0 = ldY(0);
    uint4 pre1 = ldY(1);
    #pragma unroll
    for (int ks=0; ks<6; ks++){
      // commit prefetched tile -> raw LDS (contiguous 16B/thread)
      uint4 cur = (ks&1) ? pre1 : pre0;
      *(uint4*)(&rawS[ks&1][(size_t)tid*8]) = cur;
      __syncthreads();                 // raw[ks&1] ready
      if (ks < 4){
        if (ks&1) pre1 = ldY(ks+2); else pre0 = ldY(ks+2);
      }
      // repack: column l gather (same-dword broadcast reads, conflict-free)
      const ushort* rp = rawS[ks&1];
      ushort v[8];
      #pragma unroll
      for (int j=0;j<8;j++) v[j] = rp[(8*g + j)*64 + l];
      #pragma unroll
      for (int i=0;i<4;i++)
        BtS[ks&1][l*18 + 4*g + i] = (uint)v[2*i] | ((uint)v[2*i+1] << 16);
      __syncthreads();                 // Bt[ks&1] ready
      #pragma unroll
      for (int nt=0; nt<4; nt++){
        const uint* bp = &BtS[ks&1][(nt*16 + c15)*18 + q*4];
        U4 bu;
        uint2 lo = *(const uint2*)(bp);
        uint2 hi = *(const uint2*)(bp+2);
        bu.u[0]=lo.x; bu.u[1]=lo.y; bu.u[2]=hi.x; bu.u[3]=hi.y;
        acc[nt] = __builtin_amdgcn_mfma_f32_16x16x32_bf16(afr[ks], bu.v, acc[nt], 0,0,0);
      }
    }
    uint* fb = fty + (size_t)(bb*NW + c)*32*NSX;
    int k0 = 8*g + 2*q;
    #pragma unroll
    for (int nt=0; nt<4; nt++){
      int nn = n0 + nt*16 + c15;
      if (nn < NSX){
        fb[(size_t)k0*NSX + nn]     = packbf2(acc[nt][0], acc[nt][1]);
        fb[(size_t)(k0+1)*NSX + nn] = packbf2(acc[nt][2], acc[nt][3]);
      }
    }
  } else {
    int t = bx - ylim;
    int mt = t % 3; int c = (t/3) & 31; int bb = t/96;
    int m0 = mt*64;
    const ushort* hb = hbf + (size_t)((b0+bb)*NW + c)*NPIX;
    // cooperative mapping: row r = tid>>2 (0..63), n chunk (tid&3)*8
    int xr = tid >> 2, xc = (tid & 3) << 3;
    auto ldX = [&](int ks)->uint4{
      int m = m0 + xr;
      int n = ks*32 + xc;
      uint4 p = {0u,0u,0u,0u};
      if (m < NSY && n < NSX) p = *(const uint4*)(hb + (size_t)m*NSX + n);
      return p;
    };
    auto ldA = [&](int ks)->bf16x8{
      return *(const bf16x8*)(Abfx + (size_t)(16*g + c15)*384 + ks*32 + q*8);
    };
    f32x4 acc[4];
    #pragma unroll
    for (int tt=0;tt<4;tt++) acc[tt] = (f32x4){0.f,0.f,0.f,0.f};
    uint4 pre0 = ldX(0), pre1 = ldX(1);
    bf16x8 a0 = ldA(0), a1 = ldA(1);
    int s4 = (tid & 3) * 4;
    #pragma unroll
    for (int ks=0; ks<12; ks++){
      uint4 cur = (ks&1) ? pre1 : pre0;
      bf16x8 af = (ks&1) ? a1 : a0;
      uint* btp = &BtS[ks&1][xr*18 + s4];
      btp[0] = cur.x; btp[1] = cur.y; btp[2] = cur.z; btp[3] = cur.w;
      if (ks < 10){
        if (ks&1){ pre1 = ldX(ks+2); a1 = ldA(ks+2); }
        else     { pre0 = ldX(ks+2); a0 = ldA(ks+2); }
      }
      __syncthreads();                 // Bt[ks&1] ready
      #pragma unroll
      for (int nt=0; nt<4; nt++){
        const uint* bp = &BtS[ks&1][(nt*16 + c15)*18 + q*4];
        U4 bu;
        uint2 lo = *(const uint2*)(bp);
        uint2 hi = *(const uint2*)(bp+2);
        bu.u[0]=lo.x; bu.u[1]=lo.y; bu.u[2]=hi.x; bu.u[3]=hi.y;
        acc[nt] = __builtin_amdgcn_mfma_f32_16x16x32_bf16(af, bu.v, acc[nt], 0,0,0);
      }
    }
    uint* fb = ftx + (size_t)(bb*NW + c)*32*NSY;
    int k0 = 8*g + 2*q;
    #pragma unroll
    for (int nt=0; nt<4; nt++){
      int mm = m0 + nt*16 + c15;
      if (mm < NSY){
        fb[(size_t)k0*NSY + mm]     = packbf2(acc[nt][0], acc[nt][1]);
        fb[(size_t)(k0+1)*NSY + mm] = packbf2(acc[nt][2], acc[nt][3]);
      }
    }
  }
}

// ---------------- MFMA per-mode complex channel mix (y + x in one dispatch) ----------------
__global__ __launch_bounds__(256) void k_mix2(const uint* __restrict__ fty,
    const uint* __restrict__ ftx, const ushort* __restrict__ wA,
    uint* __restrict__ oy, uint* __restrict__ ox, int ylim){
  int bx = blockIdx.x;
  const uint* ft; uint* oo; int Nlen, NT, k, bb, halfoff;
  if (bx < ylim){
    bb = bx >> 5; k = bx & 31; ft = fty; oo = oy; Nlen = NSX; NT = 23; halfoff = 0;
  } else {
    int t = bx - ylim;
    bb = t >> 5; k = t & 31; ft = ftx; oo = ox; Nlen = NSY; NT = 12; halfoff = 262144;
  }
  int tid = threadIdx.x;
  int g = tid >> 6, l = tid & 63;
  int c15 = l & 15, q = l >> 4;
  const ushort* wk = wA + halfoff + k*8192;
  // A fragments: [mt][s][pass][prec], lane row o=mt*16+c15, kk=s*32+q*8+j
  bf16x8 af[2][2][2][2];
  #pragma unroll
  for (int mt=0;mt<2;mt++)
    #pragma unroll
    for (int s=0;s<2;s++)
      #pragma unroll
      for (int ps=0;ps<2;ps++)
        #pragma unroll
        for (int pr=0;pr<2;pr++)
          af[mt][s][ps][pr] = *(const bf16x8*)(wk + ps*4096 + pr*2048
                                               + (mt*16+c15)*64 + s*32 + q*8);
  const uint* fb = ft + ((size_t)bb*1024 + (size_t)k)*Nlen;   // + in*32*Nlen + n
  uint* ob = oo + ((size_t)bb*1024 + (size_t)k)*Nlen;         // + o*32*Nlen + n
  auto ldB = [&](int nt, U4* bu){
    int n = nt*16 + c15; if (n >= Nlen) n = Nlen-1;
    #pragma unroll
    for (int s=0;s<2;s++)
      #pragma unroll
      for (int t=0;t<4;t++){
        int in = s*16 + q*4 + t;
        bu[s].u[t] = fb[(size_t)in*32*Nlen + n];
      }
  };
  U4 pre[2], cur[2];
  ldB(g, pre);
  for (int nt = g; nt < NT; nt += 4){
    cur[0] = pre[0]; cur[1] = pre[1];
    if (nt + 4 < NT) ldB(nt+4, pre);
    f32x4 acc[2][2];
    #pragma unroll
    for (int mt=0;mt<2;mt++)
      #pragma unroll
      for (int ps=0;ps<2;ps++)
        acc[mt][ps] = (f32x4){0.f,0.f,0.f,0.f};
    #pragma unroll
    for (int s=0;s<2;s++)
      #pragma unroll
      for (int mt=0;mt<2;mt++)
        #pragma unroll
        for (int ps=0;ps<2;ps++){
          acc[mt][ps] = __builtin_amdgcn_mfma_f32_16x16x32_bf16(af[mt][s][ps][0], cur[s].v, acc[mt][ps], 0,0,0);
          acc[mt][ps] = __builtin_amdgcn_mfma_f32_16x16x32_bf16(af[mt][s][ps][1], cur[s].v, acc[mt][ps], 0,0,0);
        }
    int n = nt*16 + c15;
    if (n < Nlen){
      #pragma unroll
      for (int mt=0;mt<2;mt++)
        #pragma unroll
        for (int r2=0;r2<4;r2++){
          int o = mt*16 + q*4 + r2;
          ob[(size_t)o*32*Nlen + n] = packbf2(acc[mt][0][r2], acc[mt][1][r2]);
        }
    }
  }
}

// ---------------- MFMA inverse (y+x combined), occupancy-first ----------------
__global__ __launch_bounds__(256) void k_inv(const uint* __restrict__ oyb,
    const uint* __restrict__ oxb, const ushort* __restrict__ VyCT,
    const ushort* __restrict__ VxCT, const float* __restrict__ b1,
    ushort* __restrict__ x2bf){
  __shared__ uint Bt[64*34];    // [n][k]  8.7 KB
  int bx = blockIdx.x;
  // swizzle: 6 blocks of one (bb,o) share an XCD (assumes round-robin bx%8->XCD)
  int c8 = bx & 7; int rr = bx >> 3; int slot = rr/6; int nt6 = rr - slot*6;
  int gid = slot*8 + c8;
  int bb = gid >> 5; int o = gid & 31;
  int n0 = nt6*64;
  int tid = threadIdx.x;
  int l = tid & 63, g = tid >> 6;
  int c15 = l & 15, q = l >> 4;
  const uint* oxp = oxb + (size_t)(bb*NW + o)*32*NSY;
  const uint* oyp = oyb + (size_t)(bb*NW + o)*32*NSX;
  #pragma unroll
  for (int i=0;i<8;i++){
    int idx = tid + i*256;          // < 2048
    int k = idx >> 6, n = idx & 63;
    int ng = n0 + n;
    Bt[n*34 + k] = (ng < NSX) ? oyp[(size_t)k*NSX + ng] : 0u;
  }
  __syncthreads();
  f32x4 acc[3][4];
  #pragma unroll
  for (int mt=0;mt<3;mt++)
    #pragma unroll
    for (int nt=0;nt<4;nt++) acc[mt][nt] = (f32x4){0.f,0.f,0.f,0.f};
  #pragma unroll
  for (int s=0;s<4;s++){
    bf16x8 bfr[4];
    #pragma unroll
    for (int nt=0;nt<4;nt++){
      if (s < 2){
        const uint* bp = &Bt[(nt*16 + c15)*34 + s*16 + q*4];
        U4 bu; uint2 lo = *(const uint2*)bp; uint2 hi = *(const uint2*)(bp+2);
        bu.u[0]=lo.x; bu.u[1]=lo.y; bu.u[2]=hi.x; bu.u[3]=hi.y;
        bfr[nt] = bu.v;
      } else {
        bfr[nt] = *(const bf16x8*)(VxCT + (size_t)(n0 + nt*16 + c15)*64 + (s-2)*32 + q*8);
      }
    }
    #pragma unroll
    for (int mt=0;mt<3;mt++){
      int mrow = g*48 + mt*16 + c15;
      bf16x8 afr;
      if (s < 2){
        afr = *(const bf16x8*)(VyCT + (size_t)mrow*64 + s*32 + q*8);
      } else {
        // direct global gather of ox[k][m]; rows >= NSY clamped (outputs masked)
        int mc = mrow < NSY ? mrow : (NSY-1);
        int k0 = (s-2)*16 + q*4;
        U4 au;
        #pragma unroll
        for (int j=0;j<4;j++)
          au.u[j] = oxp[(size_t)(k0+j)*NSY + mc];
        afr = au.v;
      }
      #pragma unroll
      for (int nt=0;nt<4;nt++)
        acc[mt][nt] = __builtin_amdgcn_mfma_f32_16x16x32_bf16(afr, bfr[nt], acc[mt][nt], 0,0,0);
    }
  }
  float bias = b1[o];
  ushort* xp = x2bf + (size_t)(bb*NW + o)*NPIX;
  #pragma unroll
  for (int mt=0;mt<3;mt++){
    #pragma unroll
    for (int nt=0;nt<4;nt++){
      int n = n0 + nt*16 + c15;
      if (n < NSX){
        #pragma unroll
        for (int r2=0;r2<4;r2++){
          int m = g*48 + mt*16 + q*4 + r2;
          if (m < NSY) xp[(size_t)m*NSX + n] = f2bf(gelu_f(acc[mt][nt][r2] + bias));
        }
      }
    }
  }
}

// ---------------- MFMA pointwise (iters 0-2): hbf += gelu(W2 @ x2g + b2) ----------------
__global__ __launch_bounds__(256) void k_pw2(const ushort* __restrict__ x2bf,
    const ushort* __restrict__ w2b, const float* __restrict__ b2,
    uint* __restrict__ hbfu, int b0, int nloc){
  const int HP = NPIX/2;            // 32400
  __shared__ uint Ot[32*132];       // [o][px2], stride 132 (16B-aligned rows, bank-spread)
  int blk = blockIdx.x;
  int bb = blk/254, bt = blk - bb*254;
  int pxb = bt*256;
  int tid = threadIdx.x;
  int g = tid >> 6, l = tid & 63;
  int c15 = l & 15, q = l >> 4;
  // B fragments: W2 bf16, [o][c]; col o = nt*16+c15, k = q*8+j
  bf16x8 bfr[2];
  #pragma unroll
  for (int nt=0; nt<2; nt++)
    bfr[nt] = *(const bf16x8*)(w2b + (size_t)(nt*16 + c15)*32 + q*8);
  // A fragments (gelu'd x2) + MFMA
  const ushort* xb = x2bf + ((size_t)bb*NW + q*8)*NPIX;
  f32x4 acc[4][2];
  #pragma unroll
  for (int mt=0;mt<4;mt++){
    U4 au; au.u[0]=0u; au.u[1]=0u; au.u[2]=0u; au.u[3]=0u;
    int pr = pxb + g*64 + mt*16 + c15;
    if (pr < NPIX){
      ushort v[8];
      #pragma unroll
      for (int j=0;j<8;j++) v[j] = xb[(size_t)j*NPIX + pr];
      #pragma unroll
      for (int i2=0;i2<4;i2++) au.u[i2] = (uint)v[2*i2] | ((uint)v[2*i2+1] << 16);
    }
    #pragma unroll
    for (int nt=0;nt<2;nt++){
      acc[mt][nt] = (f32x4){0.f,0.f,0.f,0.f};
      acc[mt][nt] = __builtin_amdgcn_mfma_f32_16x16x32_bf16(au.v, bfr[nt], acc[mt][nt], 0,0,0);
    }
  }
  // phase 1: bias + gelu -> LDS transpose [o][px2]
  #pragma unroll
  for (int nt=0;nt<2;nt++){
    int o = nt*16 + c15;
    float bias = b2[o];
    #pragma unroll
    for (int mt=0;mt<4;mt++){
      float v0 = gelu_f(acc[mt][nt][0] + bias);
      float v1 = gelu_f(acc[mt][nt][1] + bias);
      float v2 = gelu_f(acc[mt][nt][2] + bias);
      float v3 = gelu_f(acc[mt][nt][3] + bias);
      int px2 = g*32 + mt*8 + q*2;            // (pixel within block)/2, even
      uint2 w2v; w2v.x = packbf2(v0,v1); w2v.y = packbf2(v2,v3);
      *(uint2*)(&Ot[o*132 + px2]) = w2v;
    }
  }
  __syncthreads();
  // phase 2: coalesced residual RMW on hbf; 8 threads per o-row, 16 uints each
  int o = tid >> 3, t8 = tid & 7;
  uint* hb = hbfu + ((size_t)((b0+bb)*NW + o))*HP + (pxb>>1) + t8*16;
  const uint* lrow = &Ot[o*132 + t8*16];
  int p2g0 = (pxb>>1) + t8*16;
  #pragma unroll
  for (int jj=0; jj<16; jj+=4){
    if (p2g0 + jj + 4 <= HP){
      uint4 hv = *(const uint4*)(hb + jj);
      uint4 av = *(const uint4*)(lrow + jj);
      uint4 r;
      r.x = addbf2(hv.x, av.x); r.y = addbf2(hv.y, av.y);
      r.z = addbf2(hv.z, av.z); r.w = addbf2(hv.w, av.w);
      *(uint4*)(hb + jj) = r;
    } else {
      #pragma unroll
      for (int t=0;t<4;t++){
        if (p2g0 + jj + t < HP){
          uint hv = hb[jj+t];
          hb[jj+t] = addbf2(hv, lrow[jj+t]);
        }
      }
    }
  }
}

// ---------------- fused final: h=x4+hbf in LDS, then fc1+gelu+fc2 -> out ----------------
#define OTS 134
__global__ __launch_bounds__(256) void k_pw2f(const ushort* __restrict__ x2bf,
    const ushort* __restrict__ w2b, const float* __restrict__ b2,
    const uint* __restrict__ hbfu,
    const ushort* __restrict__ f1Tbf, const float* __restrict__ f1b,
    const float* __restrict__ f2w, const float* __restrict__ f2b,
    float* __restrict__ out, int b0){
  const int HP = NPIX/2;            // 32400
  __shared__ uint Ot[32*OTS];
  int blk = blockIdx.x;
  int bb = blk/254, bt = blk - bb*254;
  int pxb = bt*256;
  int tid = threadIdx.x;
  int g = tid >> 6, l = tid & 63;
  int c15 = l & 15, q = l >> 4;
  // ---- phase 0: W2 @ x2g (as k_pw2) ----
  bf16x8 bfr[2];
  #pragma unroll
  for (int nt=0; nt<2; nt++)
    bfr[nt] = *(const bf16x8*)(w2b + (size_t)(nt*16 + c15)*32 + q*8);
  const ushort* xb = x2bf + ((size_t)bb*NW + q*8)*NPIX;
  f32x4 acc[4][2];
  #pragma unroll
  for (int mt=0;mt<4;mt++){
    U4 au; au.u[0]=0u; au.u[1]=0u; au.u[2]=0u; au.u[3]=0u;
    int pr = pxb + g*64 + mt*16 + c15;
    if (pr < NPIX){
      ushort v[8];
      #pragma unroll
      for (int j=0;j<8;j++) v[j] = xb[(size_t)j*NPIX + pr];
      #pragma unroll
      for (int i2=0;i2<4;i2++) au.u[i2] = (uint)v[2*i2] | ((uint)v[2*i2+1] << 16);
    }
    #pragma unroll
    for (int nt=0;nt<2;nt++){
      acc[mt][nt] = (f32x4){0.f,0.f,0.f,0.f};
      acc[mt][nt] = __builtin_amdgcn_mfma_f32_16x16x32_bf16(au.v, bfr[nt], acc[mt][nt], 0,0,0);
    }
  }
  // ---- phase 1: bias (NO gelu: last block) -> Ot ----
  #pragma unroll
  for (int nt=0;nt<2;nt++){
    int o = nt*16 + c15;
    float bias = b2[o];
    #pragma unroll
    for (int mt=0;mt<4;mt++){
      float v0 = acc[mt][nt][0] + bias;
      float v1 = acc[mt][nt][1] + bias;
      float v2 = acc[mt][nt][2] + bias;
      float v3 = acc[mt][nt][3] + bias;
      int px2 = g*32 + mt*8 + q*2;
      uint2 w2v; w2v.x = packbf2(v0,v1); w2v.y = packbf2(v2,v3);
      *(uint2*)(&Ot[o*OTS + px2]) = w2v;
    }
  }
  __syncthreads();
  // ---- phase 2: h_final = hbf + x4, kept IN LDS (no global write) ----
  {
    int o = tid >> 3, t8 = tid & 7;
    const uint* hb = hbfu + ((size_t)((b0+bb)*NW + o))*HP + (pxb>>1) + t8*16;
    uint* lrow = &Ot[o*OTS + t8*16];
    int p2g0 = (pxb>>1) + t8*16;
    #pragma unroll
    for (int jj=0; jj<16; jj+=4){
      if (p2g0 + jj + 4 <= HP){
        uint4 hv = *(const uint4*)(hb + jj);
        lrow[jj+0] = addbf2(hv.x, lrow[jj+0]);
        lrow[jj+1] = addbf2(hv.y, lrow[jj+1]);
        lrow[jj+2] = addbf2(hv.z, lrow[jj+2]);
        lrow[jj+3] = addbf2(hv.w, lrow[jj+3]);
      } else {
        #pragma unroll
        for (int t=0;t<4;t++){
          if (p2g0 + jj + t < HP)
            lrow[jj+t] = addbf2(hb[jj+t], lrow[jj+t]);
        }
      }
    }
  }
  // ---- phase 3: fc1 + gelu + fc2 from Ot ----
  bf16x8 b1fr[8];
  #pragma unroll
  for (int nt=0; nt<8; nt++)
    b1fr[nt] = *(const bf16x8*)(f1Tbf + (size_t)(nt*16 + c15)*32 + q*8);
  __syncthreads();
  const ushort* Ts = (const ushort*)Ot;   // row stride 2*OTS ushorts per channel
  float fb2 = f2b[0];
  float* ob = out + (size_t)(b0+bb)*NPIX + pxb;
  #pragma unroll
  for (int mt=0;mt<4;mt++){
    int px_in = g*64 + mt*16 + c15;
    const ushort* tp = Ts + (size_t)(q*8)*(2*OTS) + px_in;
    ushort v[8];
    #pragma unroll
    for (int j2=0;j2<8;j2++) v[j2] = tp[j2*(2*OTS)];
    U4 au;
    #pragma unroll
    for (int i2=0;i2<4;i2++) au.u[i2] = (uint)v[2*i2] | ((uint)v[2*i2+1] << 16);
    f32x4 a8[8];
    #pragma unroll
    for (int nt=0; nt<8; nt++){
      a8[nt] = (f32x4){0.f,0.f,0.f,0.f};
      a8[nt] = __builtin_amdgcn_mfma_f32_16x16x32_bf16(au.v, b1fr[nt], a8[nt], 0,0,0);
    }
    float s[4] = {0.f,0.f,0.f,0.f};
    #pragma unroll
    for (int nt=0; nt<8; nt++){
      int jj = nt*16 + c15;
      float bj = f1b[jj], wj = f2w[jj];
      #pragma unroll
      for (int r2=0;r2<4;r2++) s[r2] += gelu_f(a8[nt][r2] + bj) * wj;
    }
    #pragma unroll
    for (int msk=1; msk<16; msk<<=1){
      #pragma unroll
      for (int r2=0;r2<4;r2++) s[r2] += __shfl_xor(s[r2], msk, 64);
    }
    if (c15 == 0){
      int pl = g*64 + mt*16 + q*4;
      if (pxb + pl + 4 <= NPIX){
        float4 o4 = {s[0]+fb2, s[1]+fb2, s[2]+fb2, s[3]+fb2};
        *(float4*)(ob + pl) = o4;
      }
    }
  }
}

extern "C" void kernel_launch(void* const* d_in, const int* in_sizes, int n_in,
                              void* d_out, int out_size, void* d_ws, size_t ws_size,
                              hipStream_t stream) {
  const float* x     = (const float*)d_in[0];
  const float* sx    = (const float*)d_in[1];
  const float* sy    = (const float*)d_in[2];
  const float* fc0_w = (const float*)d_in[3];
  const float* fc0_b = (const float*)d_in[4];
  const float* fw1   = (const float*)d_in[5];
  const float* fw2   = (const float*)d_in[6];
  const float* w1m   = (const float*)d_in[7];
  const float* b1    = (const float*)d_in[8];
  const float* w2m   = (const float*)d_in[9];
  const float* b2    = (const float*)d_in[10];
  const float* fc1_w = (const float*)d_in[11];
  const float* fc1_b = (const float*)d_in[12];
  const float* fc2_w = (const float*)d_in[13];
  const float* fc2_b = (const float*)d_in[14];
  float* out = (float*)d_out;

  char* wsb = (char*)d_ws;
  size_t off = 0;
  auto alloc = [&](size_t bytes)->char*{
    char* p = wsb + off;
    off = (off + bytes + 255) & ~(size_t)255;
    return p;
  };
  ushort* hbf   = (ushort*)alloc((size_t)NB*NW*NPIX*2);    // 66.4 MB (residual stream)
  ushort* Abfy  = (ushort*)alloc(64*192*2);
  ushort* Abfx  = (ushort*)alloc(64*384*2);
  ushort* VyCT  = (ushort*)alloc(192*64*2);
  ushort* VxCT  = (ushort*)alloc(384*64*2);
  ushort* f1Tbf = (ushort*)alloc(128*32*2);
  ushort* w2bf  = (ushort*)alloc(4096*2);
  float*  gx    = (float*)alloc(NSX*4);
  float*  gy    = (float*)alloc(NSY*4);
  ushort* wAbf  = (ushort*)alloc((size_t)4*2*32*4*2048*2);  // 4 MB bf16 mix weights
  const size_t fixedB = off;

  // per-batch: x2bf (4,147,200 B) ALIASES [fty | ftx | pad] (ft dead after k_mix2)
  const size_t szX2  = (size_t)NW*NPIX*2;
  const size_t szFty = (size_t)NW*32*NSX*4;
  const size_t szFtx = (size_t)NW*32*NSY*4;
  const size_t szOy  = szFty, szOx = szFtx;
  const size_t perB  = szX2 + szOy + szOx;      // 6,359,040 B

  int NC = 16;
  while (NC > 1 && fixedB + (size_t)NC*perB + 4096 > ws_size) NC >>= 1;
  char* pb = wsb + fixedB;
  ushort* x2bf = (ushort*)pb;
  uint*   fty  = (uint*)pb;                               // aliases x2bf head
  uint*   ftx  = (uint*)(pb + (size_t)NC*szFty);          // aliases x2bf tail
  uint*   oy   = (uint*)(pb + (size_t)NC*szX2);
  uint*   ox   = (uint*)((char*)oy + (size_t)NC*szOy);

  k_prep<<<96, 256, 0, stream>>>(sx, sy, fc1_w, w2m, Abfy, Abfx, VyCT, VxCT,
                                 f1Tbf, w2bf, gx, gy);
  k_fold<<<1024, 256, 0, stream>>>(fw1, fw2, w1m, wAbf);
  k_fc0<<<4050, 256, 0, stream>>>(x, gx, gy, fc0_w, fc0_b, hbf);

  for (int i=0;i<4;i++){
    for (int b0=0; b0<NB; b0+=NC){
      k_fwd<<<NC*288, 256, 0, stream>>>(hbf, Abfy, Abfx, fty, ftx, b0, NC*192);
      k_mix2<<<NC*64, 256, 0, stream>>>(fty, ftx, wAbf + (size_t)i*524288,
                                        oy, ox, NC*32);
      k_inv<<<NC*192, 256, 0, stream>>>(oy, ox, VyCT, VxCT, b1 + i*32, x2bf);
      if (i < 3){
        k_pw2<<<NC*254, 256, 0, stream>>>((const ushort*)x2bf,
                                          w2bf + (size_t)i*1024,
                                          b2 + i*32, (uint*)hbf, b0, NC);
      } else {
        k_pw2f<<<NC*254, 256, 0, stream>>>((const ushort*)x2bf,
                                           w2bf + (size_t)i*1024,
                                           b2 + i*32, (const uint*)hbf,
                                           f1Tbf, fc1_b, fc2_w, fc2_b,
                                           out, b0);
      }
    }
  }
}

// Round 11
// 797.026 us; speedup vs baseline: 1.0138x; 1.0138x over previous
//
#include <hip/hip_runtime.h>
#include <math.h>

#define NB 16
#define NSY 180
#define NSX 360
#define NCIN 16
#define NW 32
#define NMODES 32
#define NPIX (NSY*NSX)     // 64800
#define NPTS (NB*NPIX)     // 1036800

typedef unsigned int uint;
typedef unsigned short ushort;
typedef __attribute__((ext_vector_type(8))) short bf16x8;
typedef __attribute__((ext_vector_type(4))) float f32x4;

union U4 { uint u[4]; bf16x8 v; };

// tanh-gelu, exp2-folded: v*sigmoid(1.5957691*(v+0.044715 v^3))
__device__ __forceinline__ float gelu_f(float v){
  float u = v*(-2.3021681f - 0.10295335f*v*v);
  return v * __builtin_amdgcn_rcpf(1.f + exp2f(u));
}
__device__ __forceinline__ ushort f2bf(float x){
  uint u = __float_as_uint(x);
  return (ushort)((u + 0x7FFFu + ((u>>16)&1u)) >> 16);
}
// single-instruction packed f32->bf16 RNE (gfx950 v_cvt_pk_bf16_f32; a->low16)
__device__ __forceinline__ uint packbf2(float a, float b){
  uint r;
  asm("v_cvt_pk_bf16_f32 %0, %1, %2" : "=v"(r) : "v"(a), "v"(b));
  return r;
}
__device__ __forceinline__ float bf2f(ushort u){
  return __uint_as_float(((uint)u) << 16);
}
__device__ __forceinline__ uint addbf2(uint h, uint a){
  return packbf2(bf2f((ushort)(h & 0xffffu)) + bf2f((ushort)(a & 0xffffu)),
                 bf2f((ushort)(h >> 16))     + bf2f((ushort)(a >> 16)));
}

// ---------------- merged setup: prep (96 blk) + fold (1024 blk) + fc0 (4050 blk) ----------------
__global__ __launch_bounds__(256) void k_setup(const float* __restrict__ sx,
    const float* __restrict__ sy, const float* __restrict__ fc1_w,
    const float* __restrict__ w2m, const float* __restrict__ fw1,
    const float* __restrict__ fw2, const float* __restrict__ w1m,
    const float* __restrict__ x, const float* __restrict__ fc0_w,
    const float* __restrict__ fc0_b,
    ushort* __restrict__ Abfy, ushort* __restrict__ Abfx,
    ushort* __restrict__ VyCT, ushort* __restrict__ VxCT,
    ushort* __restrict__ f1Tbf, ushort* __restrict__ w2bf,
    ushort* __restrict__ wAbf, ushort* __restrict__ hbf){
  int bid = blockIdx.x;
  if (bid < 96){
    // ---- prep ----
    int idx = bid*256 + threadIdx.x;
    float sx0 = sx[0], sxL = sx[NSX-1];
    float sy0 = sy[0], syL = sy[NSY-1];
    const float scy = 0.07453559924999298980f;   // 1/sqrt(180)
    const float scx = 0.05270462766947298886f;   // 1/sqrt(360)
    if (idx < 64*192){
      int kri = idx/192, m = idx%192;
      float val = 0.f;
      if (m < NSY){
        int k = kri>>1;
        float p = (sy[m]-sy0)/(syL-sy0);
        float ang = -6.2831853071795864769f*(float)k*p;
        val = ((kri&1)? sinf(ang) : cosf(ang))*scy;
      }
      Abfy[idx] = f2bf(val);
    }
    if (idx < 192*64){
      int m = idx/64, kri = idx%64;
      float val = 0.f;
      if (m < NSY){
        int k = kri>>1;
        float p = (sy[m]-sy0)/(syL-sy0);
        float ang = -6.2831853071795864769f*(float)k*p;
        val = ((kri&1)? sinf(ang) : cosf(ang))*scy;
      }
      VyCT[idx] = f2bf(val);
    }
    if (idx < 64*384){
      int kri = idx/384, n = idx%384;
      float val = 0.f;
      if (n < NSX){
        int k = kri>>1;
        float p = (sx[n]-sx0)/(sxL-sx0);
        float ang = -6.2831853071795864769f*(float)k*p;
        val = ((kri&1)? sinf(ang) : cosf(ang))*scx;
      }
      Abfx[idx] = f2bf(val);
    }
    if (idx < 384*64){
      int n = idx/64, kri = idx%64;
      float val = 0.f;
      if (n < NSX){
        int k = kri>>1;
        float p = (sx[n]-sx0)/(sxL-sx0);
        float ang = -6.2831853071795864769f*(float)k*p;
        val = ((kri&1)? sinf(ang) : cosf(ang))*scx;
      }
      VxCT[idx] = f2bf(val);
    }
    if (idx < 128*32){
      int j = idx >> 5, c = idx & 31;
      f1Tbf[idx] = f2bf(fc1_w[c*128 + j]);
    }
    if (idx < 4096){
      w2bf[idx] = f2bf(w2m[idx]);
    }
  } else if (bid < 96 + 1024){
    // ---- fold: w1-folded complex mix weights -> bf16 hi/lo MFMA A-matrices ----
    int id = (bid-96)*256 + threadIdx.x;      // 0..262143
    int half = id >> 17;
    int r = id & 131071;
    int i  = r >> 15;
    int in = (r >> 10) & 31;
    int k  = (r >> 5) & 31;
    int o  = r & 31;
    const float* src = half ? fw2 : fw1;
    const float* wm  = w1m + i*1024 + o*32;
    const float* sp  = src + ((size_t)((i*32+in)*1024 + k))*2;
    float sR = 0.f, sI = 0.f;
    #pragma unroll
    for (int c=0;c<32;c++){
      float w = wm[c];
      sR += w * sp[c*64];
      sI += w * sp[c*64+1];
    }
    ushort rH = f2bf(sR);  ushort rL = f2bf(sR - bf2f(rH));
    ushort iH = f2bf(sI);  ushort iL = f2bf(sI - bf2f(iH));
    ushort nH = f2bf(-sI); ushort nL = f2bf(-sI - bf2f(nH));
    ushort* base = wAbf + (((size_t)((i*2 + half)*32 + k)) << 13);  // *8192
    int oi = o*64 + 2*in;
    base[oi]          = rH;  base[oi+1]        = nH;   // OR hi
    base[2048 + oi]   = rL;  base[2048 + oi+1] = nL;   // OR lo
    base[4096 + oi]   = iH;  base[4096 + oi+1] = rH;   // OI hi
    base[6144 + oi]   = iL;  base[6144 + oi+1] = rL;   // OI lo
  } else {
    // ---- fc0 -> hbf (grid values computed inline; no gx/gy dependency) ----
    int p = (bid-1120)*256 + threadIdx.x;
    if (p >= NPTS) return;
    int b = p/NPIX, r = p%NPIX, m = r/NSX, n = r%NSX;
    const float* xp = x + (size_t)p*NCIN;
    float4 x0 = *(const float4*)(xp);
    float4 x1 = *(const float4*)(xp+4);
    float4 x2 = *(const float4*)(xp+8);
    float4 x3 = *(const float4*)(xp+12);
    float xv[NCIN+2] = {x0.x,x0.y,x0.z,x0.w, x1.x,x1.y,x1.z,x1.w,
                        x2.x,x2.y,x2.z,x2.w, x3.x,x3.y,x3.z,x3.w, 0.f,0.f};
    xv[16] = (sx[n]-sx[0])/sx[NSX-1];
    xv[17] = (sy[m]-sy[0])/sy[NSY-1];
    float acc[NW];
    #pragma unroll
    for (int o=0;o<NW;o++) acc[o] = fc0_b[o];
    #pragma unroll
    for (int j=0;j<NCIN+2;j++){
      float v = xv[j];
      #pragma unroll
      for (int o=0;o<NW;o++) acc[o] += v*fc0_w[j*32+o];
    }
    ushort* hq = hbf + (size_t)b*NW*NPIX + r;
    #pragma unroll
    for (int o=0;o<NW;o++) hq[(size_t)o*NPIX] = f2bf(acc[o]);
  }
}

// ---------------- merged MFMA forward DFTs (y + x in one dispatch) ----------------
// v4: y-branch rawS repack is WAVE-LOCAL (wave g writes rows 8g..8g+7, reads the
// same rows) -> the raw-ready __syncthreads is removed; in-wave LDS ordering is
// handled by compiler-inserted lgkmcnt. Barriers per y-block: 12 -> 6.
__global__ __launch_bounds__(256) void k_fwd(const ushort* __restrict__ hbf,
    const ushort* __restrict__ Abfy, const ushort* __restrict__ Abfx,
    uint* __restrict__ fty, uint* __restrict__ ftx, int b0, int ylim){
  __shared__ ushort rawS[2][32*64];   // 2 x 4KB raw tile (y-branch, wave-local rows)
  __shared__ uint   BtS[2][64*18];    // 2 x 4.6KB packed B
  int bx = blockIdx.x;
  int tid = threadIdx.x;
  int l = tid & 63, g = tid >> 6;
  int c15 = l & 15, q = l >> 4;
  if (bx < ylim){
    int nt6 = bx % 6; int c = (bx/6) & 31; int bb = bx/192;
    int n0 = nt6*64;
    const ushort* hb = hbf + (size_t)((b0+bb)*NW + c)*NPIX;
    // cooperative tile load mapping: row r = tid>>3 (0..31), col chunk (tid&7)*8
    int yr = tid >> 3, yc = (tid & 7) << 3;
    auto ldY = [&](int ks)->uint4{
      int m = ks*32 + yr;
      int gc = n0 + yc;
      uint4 p = {0u,0u,0u,0u};
      if (m < NSY && gc < NSX) p = *(const uint4*)(hb + (size_t)m*NSX + gc);
      return p;
    };
    bf16x8 afr[6];
    #pragma unroll
    for (int ks=0; ks<6; ks++)
      afr[ks] = *(const bf16x8*)(Abfy + (size_t)(16*g + c15)*192 + ks*32 + q*8);
    f32x4 acc[4];
    #pragma unroll
    for (int t=0;t<4;t++) acc[t] = (f32x4){0.f,0.f,0.f,0.f};
    uint4 pre0 = ldY(0);
    uint4 pre1 = ldY(1);
    #pragma unroll
    for (int ks=0; ks<6; ks++){
      // commit prefetched tile -> raw LDS (wave-local rows; no barrier needed)
      uint4 cur = (ks&1) ? pre1 : pre0;
      *(uint4*)(&rawS[ks&1][(size_t)tid*8]) = cur;
      if (ks < 4){
        if (ks&1) pre1 = ldY(ks+2); else pre0 = ldY(ks+2);
      }
      // repack: wave-local column gather (rows 8g..8g+7 written by this wave)
      const ushort* rp = rawS[ks&1];
      ushort v[8];
      #pragma unroll
      for (int j=0;j<8;j++) v[j] = rp[(8*g + j)*64 + l];
      #pragma unroll
      for (int i=0;i<4;i++)
        BtS[ks&1][l*18 + 4*g + i] = (uint)v[2*i] | ((uint)v[2*i+1] << 16);
      __syncthreads();                 // Bt[ks&1] ready (also orders Bt reuse)
      #pragma unroll
      for (int nt=0; nt<4; nt++){
        const uint* bp = &BtS[ks&1][(nt*16 + c15)*18 + q*4];
        U4 bu;
        uint2 lo = *(const uint2*)(bp);
        uint2 hi = *(const uint2*)(bp+2);
        bu.u[0]=lo.x; bu.u[1]=lo.y; bu.u[2]=hi.x; bu.u[3]=hi.y;
        acc[nt] = __builtin_amdgcn_mfma_f32_16x16x32_bf16(afr[ks], bu.v, acc[nt], 0,0,0);
      }
    }
    uint* fb = fty + (size_t)(bb*NW + c)*32*NSX;
    int k0 = 8*g + 2*q;
    #pragma unroll
    for (int nt=0; nt<4; nt++){
      int nn = n0 + nt*16 + c15;
      if (nn < NSX){
        fb[(size_t)k0*NSX + nn]     = packbf2(acc[nt][0], acc[nt][1]);
        fb[(size_t)(k0+1)*NSX + nn] = packbf2(acc[nt][2], acc[nt][3]);
      }
    }
  } else {
    int t = bx - ylim;
    int mt = t % 3; int c = (t/3) & 31; int bb = t/96;
    int m0 = mt*64;
    const ushort* hb = hbf + (size_t)((b0+bb)*NW + c)*NPIX;
    // cooperative mapping: row r = tid>>2 (0..63), n chunk (tid&3)*8
    int xr = tid >> 2, xc = (tid & 3) << 3;
    auto ldX = [&](int ks)->uint4{
      int m = m0 + xr;
      int n = ks*32 + xc;
      uint4 p = {0u,0u,0u,0u};
      if (m < NSY && n < NSX) p = *(const uint4*)(hb + (size_t)m*NSX + n);
      return p;
    };
    auto ldA = [&](int ks)->bf16x8{
      return *(const bf16x8*)(Abfx + (size_t)(16*g + c15)*384 + ks*32 + q*8);
    };
    f32x4 acc[4];
    #pragma unroll
    for (int tt=0;tt<4;tt++) acc[tt] = (f32x4){0.f,0.f,0.f,0.f};
    uint4 pre0 = ldX(0), pre1 = ldX(1);
    bf16x8 a0 = ldA(0), a1 = ldA(1);
    int s4 = (tid & 3) * 4;
    #pragma unroll
    for (int ks=0; ks<12; ks++){
      uint4 cur = (ks&1) ? pre1 : pre0;
      bf16x8 af = (ks&1) ? a1 : a0;
      uint* btp = &BtS[ks&1][xr*18 + s4];
      btp[0] = cur.x; btp[1] = cur.y; btp[2] = cur.z; btp[3] = cur.w;
      if (ks < 10){
        if (ks&1){ pre1 = ldX(ks+2); a1 = ldA(ks+2); }
        else     { pre0 = ldX(ks+2); a0 = ldA(ks+2); }
      }
      __syncthreads();                 // Bt[ks&1] ready
      #pragma unroll
      for (int nt=0; nt<4; nt++){
        const uint* bp = &BtS[ks&1][(nt*16 + c15)*18 + q*4];
        U4 bu;
        uint2 lo = *(const uint2*)(bp);
        uint2 hi = *(const uint2*)(bp+2);
        bu.u[0]=lo.x; bu.u[1]=lo.y; bu.u[2]=hi.x; bu.u[3]=hi.y;
        acc[nt] = __builtin_amdgcn_mfma_f32_16x16x32_bf16(af, bu.v, acc[nt], 0,0,0);
      }
    }
    uint* fb = ftx + (size_t)(bb*NW + c)*32*NSY;
    int k0 = 8*g + 2*q;
    #pragma unroll
    for (int nt=0; nt<4; nt++){
      int mm = m0 + nt*16 + c15;
      if (mm < NSY){
        fb[(size_t)k0*NSY + mm]     = packbf2(acc[nt][0], acc[nt][1]);
        fb[(size_t)(k0+1)*NSY + mm] = packbf2(acc[nt][2], acc[nt][3]);
      }
    }
  }
}

// ---------------- MFMA per-mode complex channel mix (y + x in one dispatch) ----------------
__global__ __launch_bounds__(256) void k_mix2(const uint* __restrict__ fty,
    const uint* __restrict__ ftx, const ushort* __restrict__ wA,
    uint* __restrict__ oy, uint* __restrict__ ox, int ylim){
  int bx = blockIdx.x;
  const uint* ft; uint* oo; int Nlen, NT, k, bb, halfoff;
  if (bx < ylim){
    bb = bx >> 5; k = bx & 31; ft = fty; oo = oy; Nlen = NSX; NT = 23; halfoff = 0;
  } else {
    int t = bx - ylim;
    bb = t >> 5; k = t & 31; ft = ftx; oo = ox; Nlen = NSY; NT = 12; halfoff = 262144;
  }
  int tid = threadIdx.x;
  int g = tid >> 6, l = tid & 63;
  int c15 = l & 15, q = l >> 4;
  const ushort* wk = wA + halfoff + k*8192;
  // A fragments: [mt][s][pass][prec], lane row o=mt*16+c15, kk=s*32+q*8+j
  bf16x8 af[2][2][2][2];
  #pragma unroll
  for (int mt=0;mt<2;mt++)
    #pragma unroll
    for (int s=0;s<2;s++)
      #pragma unroll
      for (int ps=0;ps<2;ps++)
        #pragma unroll
        for (int pr=0;pr<2;pr++)
          af[mt][s][ps][pr] = *(const bf16x8*)(wk + ps*4096 + pr*2048
                                               + (mt*16+c15)*64 + s*32 + q*8);
  const uint* fb = ft + ((size_t)bb*1024 + (size_t)k)*Nlen;   // + in*32*Nlen + n
  uint* ob = oo + ((size_t)bb*1024 + (size_t)k)*Nlen;         // + o*32*Nlen + n
  auto ldB = [&](int nt, U4* bu){
    int n = nt*16 + c15; if (n >= Nlen) n = Nlen-1;
    #pragma unroll
    for (int s=0;s<2;s++)
      #pragma unroll
      for (int t=0;t<4;t++){
        int in = s*16 + q*4 + t;
        bu[s].u[t] = fb[(size_t)in*32*Nlen + n];
      }
  };
  U4 pre[2], cur[2];
  ldB(g, pre);
  for (int nt = g; nt < NT; nt += 4){
    cur[0] = pre[0]; cur[1] = pre[1];
    if (nt + 4 < NT) ldB(nt+4, pre);
    f32x4 acc[2][2];
    #pragma unroll
    for (int mt=0;mt<2;mt++)
      #pragma unroll
      for (int ps=0;ps<2;ps++)
        acc[mt][ps] = (f32x4){0.f,0.f,0.f,0.f};
    #pragma unroll
    for (int s=0;s<2;s++)
      #pragma unroll
      for (int mt=0;mt<2;mt++)
        #pragma unroll
        for (int ps=0;ps<2;ps++){
          acc[mt][ps] = __builtin_amdgcn_mfma_f32_16x16x32_bf16(af[mt][s][ps][0], cur[s].v, acc[mt][ps], 0,0,0);
          acc[mt][ps] = __builtin_amdgcn_mfma_f32_16x16x32_bf16(af[mt][s][ps][1], cur[s].v, acc[mt][ps], 0,0,0);
        }
    int n = nt*16 + c15;
    if (n < Nlen){
      #pragma unroll
      for (int mt=0;mt<2;mt++)
        #pragma unroll
        for (int r2=0;r2<4;r2++){
          int o = mt*16 + q*4 + r2;
          ob[(size_t)o*32*Nlen + n] = packbf2(acc[mt][0][r2], acc[mt][1][r2]);
        }
    }
  }
}

// ---------------- MFMA inverse (y+x combined), occupancy-first ----------------
__global__ __launch_bounds__(256) void k_inv(const uint* __restrict__ oyb,
    const uint* __restrict__ oxb, const ushort* __restrict__ VyCT,
    const ushort* __restrict__ VxCT, const float* __restrict__ b1,
    ushort* __restrict__ x2bf){
  __shared__ uint Bt[64*34];    // [n][k]  8.7 KB
  int bx = blockIdx.x;
  // swizzle: 6 blocks of one (bb,o) share an XCD (assumes round-robin bx%8->XCD)
  int c8 = bx & 7; int rr = bx >> 3; int slot = rr/6; int nt6 = rr - slot*6;
  int gid = slot*8 + c8;
  int bb = gid >> 5; int o = gid & 31;
  int n0 = nt6*64;
  int tid = threadIdx.x;
  int l = tid & 63, g = tid >> 6;
  int c15 = l & 15, q = l >> 4;
  const uint* oxp = oxb + (size_t)(bb*NW + o)*32*NSY;
  const uint* oyp = oyb + (size_t)(bb*NW + o)*32*NSX;
  #pragma unroll
  for (int i=0;i<8;i++){
    int idx = tid + i*256;          // < 2048
    int k = idx >> 6, n = idx & 63;
    int ng = n0 + n;
    Bt[n*34 + k] = (ng < NSX) ? oyp[(size_t)k*NSX + ng] : 0u;
  }
  __syncthreads();
  f32x4 acc[3][4];
  #pragma unroll
  for (int mt=0;mt<3;mt++)
    #pragma unroll
    for (int nt=0;nt<4;nt++) acc[mt][nt] = (f32x4){0.f,0.f,0.f,0.f};
  #pragma unroll
  for (int s=0;s<4;s++){
    bf16x8 bfr[4];
    #pragma unroll
    for (int nt=0;nt<4;nt++){
      if (s < 2){
        const uint* bp = &Bt[(nt*16 + c15)*34 + s*16 + q*4];
        U4 bu; uint2 lo = *(const uint2*)bp; uint2 hi = *(const uint2*)(bp+2);
        bu.u[0]=lo.x; bu.u[1]=lo.y; bu.u[2]=hi.x; bu.u[3]=hi.y;
        bfr[nt] = bu.v;
      } else {
        bfr[nt] = *(const bf16x8*)(VxCT + (size_t)(n0 + nt*16 + c15)*64 + (s-2)*32 + q*8);
      }
    }
    #pragma unroll
    for (int mt=0;mt<3;mt++){
      int mrow = g*48 + mt*16 + c15;
      bf16x8 afr;
      if (s < 2){
        afr = *(const bf16x8*)(VyCT + (size_t)mrow*64 + s*32 + q*8);
      } else {
        // direct global gather of ox[k][m]; rows >= NSY clamped (outputs masked)
        int mc = mrow < NSY ? mrow : (NSY-1);
        int k0 = (s-2)*16 + q*4;
        U4 au;
        #pragma unroll
        for (int j=0;j<4;j++)
          au.u[j] = oxp[(size_t)(k0+j)*NSY + mc];
        afr = au.v;
      }
      #pragma unroll
      for (int nt=0;nt<4;nt++)
        acc[mt][nt] = __builtin_amdgcn_mfma_f32_16x16x32_bf16(afr, bfr[nt], acc[mt][nt], 0,0,0);
    }
  }
  float bias = b1[o];
  ushort* xp = x2bf + (size_t)(bb*NW + o)*NPIX;
  #pragma unroll
  for (int mt=0;mt<3;mt++){
    #pragma unroll
    for (int nt=0;nt<4;nt++){
      int n = n0 + nt*16 + c15;
      if (n < NSX){
        #pragma unroll
        for (int r2=0;r2<4;r2++){
          int m = g*48 + mt*16 + q*4 + r2;
          if (m < NSY) xp[(size_t)m*NSX + n] = f2bf(gelu_f(acc[mt][nt][r2] + bias));
        }
      }
    }
  }
}

// ---------------- MFMA pointwise (iters 0-2): hbf += gelu(W2 @ x2g + b2) ----------------
__global__ __launch_bounds__(256) void k_pw2(const ushort* __restrict__ x2bf,
    const ushort* __restrict__ w2b, const float* __restrict__ b2,
    uint* __restrict__ hbfu, int b0, int nloc){
  const int HP = NPIX/2;            // 32400
  __shared__ uint Ot[32*132];       // [o][px2], stride 132 (16B-aligned rows, bank-spread)
  int blk = blockIdx.x;
  int bb = blk/254, bt = blk - bb*254;
  int pxb = bt*256;
  int tid = threadIdx.x;
  int g = tid >> 6, l = tid & 63;
  int c15 = l & 15, q = l >> 4;
  // B fragments: W2 bf16, [o][c]; col o = nt*16+c15, k = q*8+j
  bf16x8 bfr[2];
  #pragma unroll
  for (int nt=0; nt<2; nt++)
    bfr[nt] = *(const bf16x8*)(w2b + (size_t)(nt*16 + c15)*32 + q*8);
  // A fragments (gelu'd x2) + MFMA
  const ushort* xb = x2bf + ((size_t)bb*NW + q*8)*NPIX;
  f32x4 acc[4][2];
  #pragma unroll
  for (int mt=0;mt<4;mt++){
    U4 au; au.u[0]=0u; au.u[1]=0u; au.u[2]=0u; au.u[3]=0u;
    int pr = pxb + g*64 + mt*16 + c15;
    if (pr < NPIX){
      ushort v[8];
      #pragma unroll
      for (int j=0;j<8;j++) v[j] = xb[(size_t)j*NPIX + pr];
      #pragma unroll
      for (int i2=0;i2<4;i2++) au.u[i2] = (uint)v[2*i2] | ((uint)v[2*i2+1] << 16);
    }
    #pragma unroll
    for (int nt=0;nt<2;nt++){
      acc[mt][nt] = (f32x4){0.f,0.f,0.f,0.f};
      acc[mt][nt] = __builtin_amdgcn_mfma_f32_16x16x32_bf16(au.v, bfr[nt], acc[mt][nt], 0,0,0);
    }
  }
  // phase 1: bias + gelu -> LDS transpose [o][px2]
  #pragma unroll
  for (int nt=0;nt<2;nt++){
    int o = nt*16 + c15;
    float bias = b2[o];
    #pragma unroll
    for (int mt=0;mt<4;mt++){
      float v0 = gelu_f(acc[mt][nt][0] + bias);
      float v1 = gelu_f(acc[mt][nt][1] + bias);
      float v2 = gelu_f(acc[mt][nt][2] + bias);
      float v3 = gelu_f(acc[mt][nt][3] + bias);
      int px2 = g*32 + mt*8 + q*2;            // (pixel within block)/2, even
      uint2 w2v; w2v.x = packbf2(v0,v1); w2v.y = packbf2(v2,v3);
      *(uint2*)(&Ot[o*132 + px2]) = w2v;
    }
  }
  __syncthreads();
  // phase 2: coalesced residual RMW on hbf; 8 threads per o-row, 16 uints each
  int o = tid >> 3, t8 = tid & 7;
  uint* hb = hbfu + ((size_t)((b0+bb)*NW + o))*HP + (pxb>>1) + t8*16;
  const uint* lrow = &Ot[o*132 + t8*16];
  int p2g0 = (pxb>>1) + t8*16;
  #pragma unroll
  for (int jj=0; jj<16; jj+=4){
    if (p2g0 + jj + 4 <= HP){
      uint4 hv = *(const uint4*)(hb + jj);
      uint4 av = *(const uint4*)(lrow + jj);
      uint4 r;
      r.x = addbf2(hv.x, av.x); r.y = addbf2(hv.y, av.y);
      r.z = addbf2(hv.z, av.z); r.w = addbf2(hv.w, av.w);
      *(uint4*)(hb + jj) = r;
    } else {
      #pragma unroll
      for (int t=0;t<4;t++){
        if (p2g0 + jj + t < HP){
          uint hv = hb[jj+t];
          hb[jj+t] = addbf2(hv, lrow[jj+t]);
        }
      }
    }
  }
}

// ---------------- fused final: h=x4+hbf in LDS, then fc1+gelu+fc2 -> out ----------------
#define OTS 134
__global__ __launch_bounds__(256) void k_pw2f(const ushort* __restrict__ x2bf,
    const ushort* __restrict__ w2b, const float* __restrict__ b2,
    const uint* __restrict__ hbfu,
    const ushort* __restrict__ f1Tbf, const float* __restrict__ f1b,
    const float* __restrict__ f2w, const float* __restrict__ f2b,
    float* __restrict__ out, int b0){
  const int HP = NPIX/2;            // 32400
  __shared__ uint Ot[32*OTS];
  int blk = blockIdx.x;
  int bb = blk/254, bt = blk - bb*254;
  int pxb = bt*256;
  int tid = threadIdx.x;
  int g = tid >> 6, l = tid & 63;
  int c15 = l & 15, q = l >> 4;
  // ---- phase 0: W2 @ x2g (as k_pw2) ----
  bf16x8 bfr[2];
  #pragma unroll
  for (int nt=0; nt<2; nt++)
    bfr[nt] = *(const bf16x8*)(w2b + (size_t)(nt*16 + c15)*32 + q*8);
  const ushort* xb = x2bf + ((size_t)bb*NW + q*8)*NPIX;
  f32x4 acc[4][2];
  #pragma unroll
  for (int mt=0;mt<4;mt++){
    U4 au; au.u[0]=0u; au.u[1]=0u; au.u[2]=0u; au.u[3]=0u;
    int pr = pxb + g*64 + mt*16 + c15;
    if (pr < NPIX){
      ushort v[8];
      #pragma unroll
      for (int j=0;j<8;j++) v[j] = xb[(size_t)j*NPIX + pr];
      #pragma unroll
      for (int i2=0;i2<4;i2++) au.u[i2] = (uint)v[2*i2] | ((uint)v[2*i2+1] << 16);
    }
    #pragma unroll
    for (int nt=0;nt<2;nt++){
      acc[mt][nt] = (f32x4){0.f,0.f,0.f,0.f};
      acc[mt][nt] = __builtin_amdgcn_mfma_f32_16x16x32_bf16(au.v, bfr[nt], acc[mt][nt], 0,0,0);
    }
  }
  // ---- phase 1: bias (NO gelu: last block) -> Ot ----
  #pragma unroll
  for (int nt=0;nt<2;nt++){
    int o = nt*16 + c15;
    float bias = b2[o];
    #pragma unroll
    for (int mt=0;mt<4;mt++){
      float v0 = acc[mt][nt][0] + bias;
      float v1 = acc[mt][nt][1] + bias;
      float v2 = acc[mt][nt][2] + bias;
      float v3 = acc[mt][nt][3] + bias;
      int px2 = g*32 + mt*8 + q*2;
      uint2 w2v; w2v.x = packbf2(v0,v1); w2v.y = packbf2(v2,v3);
      *(uint2*)(&Ot[o*OTS + px2]) = w2v;
    }
  }
  __syncthreads();
  // ---- phase 2: h_final = hbf + x4, kept IN LDS (no global write) ----
  {
    int o = tid >> 3, t8 = tid & 7;
    const uint* hb = hbfu + ((size_t)((b0+bb)*NW + o))*HP + (pxb>>1) + t8*16;
    uint* lrow = &Ot[o*OTS + t8*16];
    int p2g0 = (pxb>>1) + t8*16;
    #pragma unroll
    for (int jj=0; jj<16; jj+=4){
      if (p2g0 + jj + 4 <= HP){
        uint4 hv = *(const uint4*)(hb + jj);
        lrow[jj+0] = addbf2(hv.x, lrow[jj+0]);
        lrow[jj+1] = addbf2(hv.y, lrow[jj+1]);
        lrow[jj+2] = addbf2(hv.z, lrow[jj+2]);
        lrow[jj+3] = addbf2(hv.w, lrow[jj+3]);
      } else {
        #pragma unroll
        for (int t=0;t<4;t++){
          if (p2g0 + jj + t < HP)
            lrow[jj+t] = addbf2(hb[jj+t], lrow[jj+t]);
        }
      }
    }
  }
  // ---- phase 3: fc1 + gelu + fc2 from Ot ----
  bf16x8 b1fr[8];
  #pragma unroll
  for (int nt=0; nt<8; nt++)
    b1fr[nt] = *(const bf16x8*)(f1Tbf + (size_t)(nt*16 + c15)*32 + q*8);
  __syncthreads();
  const ushort* Ts = (const ushort*)Ot;   // row stride 2*OTS ushorts per channel
  float fb2 = f2b[0];
  float* ob = out + (size_t)(b0+bb)*NPIX + pxb;
  #pragma unroll
  for (int mt=0;mt<4;mt++){
    int px_in = g*64 + mt*16 + c15;
    const ushort* tp = Ts + (size_t)(q*8)*(2*OTS) + px_in;
    ushort v[8];
    #pragma unroll
    for (int j2=0;j2<8;j2++) v[j2] = tp[j2*(2*OTS)];
    U4 au;
    #pragma unroll
    for (int i2=0;i2<4;i2++) au.u[i2] = (uint)v[2*i2] | ((uint)v[2*i2+1] << 16);
    f32x4 a8[8];
    #pragma unroll
    for (int nt=0; nt<8; nt++){
      a8[nt] = (f32x4){0.f,0.f,0.f,0.f};
      a8[nt] = __builtin_amdgcn_mfma_f32_16x16x32_bf16(au.v, b1fr[nt], a8[nt], 0,0,0);
    }
    float s[4] = {0.f,0.f,0.f,0.f};
    #pragma unroll
    for (int nt=0; nt<8; nt++){
      int jj = nt*16 + c15;
      float bj = f1b[jj], wj = f2w[jj];
      #pragma unroll
      for (int r2=0;r2<4;r2++) s[r2] += gelu_f(a8[nt][r2] + bj) * wj;
    }
    #pragma unroll
    for (int msk=1; msk<16; msk<<=1){
      #pragma unroll
      for (int r2=0;r2<4;r2++) s[r2] += __shfl_xor(s[r2], msk, 64);
    }
    if (c15 == 0){
      int pl = g*64 + mt*16 + q*4;
      if (pxb + pl + 4 <= NPIX){
        float4 o4 = {s[0]+fb2, s[1]+fb2, s[2]+fb2, s[3]+fb2};
        *(float4*)(ob + pl) = o4;
      }
    }
  }
}

extern "C" void kernel_launch(void* const* d_in, const int* in_sizes, int n_in,
                              void* d_out, int out_size, void* d_ws, size_t ws_size,
                              hipStream_t stream) {
  const float* x     = (const float*)d_in[0];
  const float* sx    = (const float*)d_in[1];
  const float* sy    = (const float*)d_in[2];
  const float* fc0_w = (const float*)d_in[3];
  const float* fc0_b = (const float*)d_in[4];
  const float* fw1   = (const float*)d_in[5];
  const float* fw2   = (const float*)d_in[6];
  const float* w1m   = (const float*)d_in[7];
  const float* b1    = (const float*)d_in[8];
  const float* w2m   = (const float*)d_in[9];
  const float* b2    = (const float*)d_in[10];
  const float* fc1_w = (const float*)d_in[11];
  const float* fc1_b = (const float*)d_in[12];
  const float* fc2_w = (const float*)d_in[13];
  const float* fc2_b = (const float*)d_in[14];
  float* out = (float*)d_out;

  char* wsb = (char*)d_ws;
  size_t off = 0;
  auto alloc = [&](size_t bytes)->char*{
    char* p = wsb + off;
    off = (off + bytes + 255) & ~(size_t)255;
    return p;
  };
  ushort* hbf   = (ushort*)alloc((size_t)NB*NW*NPIX*2);    // 66.4 MB (residual stream)
  ushort* Abfy  = (ushort*)alloc(64*192*2);
  ushort* Abfx  = (ushort*)alloc(64*384*2);
  ushort* VyCT  = (ushort*)alloc(192*64*2);
  ushort* VxCT  = (ushort*)alloc(384*64*2);
  ushort* f1Tbf = (ushort*)alloc(128*32*2);
  ushort* w2bf  = (ushort*)alloc(4096*2);
  ushort* wAbf  = (ushort*)alloc((size_t)4*2*32*4*2048*2);  // 4 MB bf16 mix weights
  const size_t fixedB = off;

  // per-batch: x2bf (4,147,200 B) ALIASES [fty | ftx | pad] (ft dead after k_mix2)
  const size_t szX2  = (size_t)NW*NPIX*2;
  const size_t szFty = (size_t)NW*32*NSX*4;
  const size_t szFtx = (size_t)NW*32*NSY*4;
  const size_t szOy  = szFty, szOx = szFtx;
  const size_t perB  = szX2 + szOy + szOx;      // 6,359,040 B

  int NC = 16;
  while (NC > 1 && fixedB + (size_t)NC*perB + 4096 > ws_size) NC >>= 1;
  char* pb = wsb + fixedB;
  ushort* x2bf = (ushort*)pb;
  uint*   fty  = (uint*)pb;                               // aliases x2bf head
  uint*   ftx  = (uint*)(pb + (size_t)NC*szFty);          // aliases x2bf tail
  uint*   oy   = (uint*)(pb + (size_t)NC*szX2);
  uint*   ox   = (uint*)((char*)oy + (size_t)NC*szOy);

  k_setup<<<96 + 1024 + 4050, 256, 0, stream>>>(sx, sy, fc1_w, w2m, fw1, fw2,
                                                w1m, x, fc0_w, fc0_b,
                                                Abfy, Abfx, VyCT, VxCT,
                                                f1Tbf, w2bf, wAbf, hbf);

  for (int i=0;i<4;i++){
    for (int b0=0; b0<NB; b0+=NC){
      k_fwd<<<NC*288, 256, 0, stream>>>(hbf, Abfy, Abfx, fty, ftx, b0, NC*192);
      k_mix2<<<NC*64, 256, 0, stream>>>(fty, ftx, wAbf + (size_t)i*524288,
                                        oy, ox, NC*32);
      k_inv<<<NC*192, 256, 0, stream>>>(oy, ox, VyCT, VxCT, b1 + i*32, x2bf);
      if (i < 3){
        k_pw2<<<NC*254, 256, 0, stream>>>((const ushort*)x2bf,
                                          w2bf + (size_t)i*1024,
                                          b2 + i*32, (uint*)hbf, b0, NC);
      } else {
        k_pw2f<<<NC*254, 256, 0, stream>>>((const ushort*)x2bf,
                                           w2bf + (size_t)i*1024,
                                           b2 + i*32, (const uint*)hbf,
                                           f1Tbf, fc1_b, fc2_w, fc2_b,
                                           out, b0);
      }
    }
  }
}